// Round 15
// baseline (2378.076 us; speedup 1.0000x reference)
//
#include <hip/hip_runtime.h>
#include <hip/hip_bf16.h>

// Sizes (fixed): T=512 tokens, D=256 embed, L=256 lstm, H=512 hidden. 4L=1024.

typedef _Float16 h2v __attribute__((ext_vector_type(2)));
typedef unsigned int u32x8 __attribute__((ext_vector_type(8)));

#define BC(x) __builtin_bit_cast(h2v, (x))

__device__ __forceinline__ float fdot2f(h2v a, h2v b, float c) {
#if __has_builtin(__builtin_amdgcn_fdot2)
    return __builtin_amdgcn_fdot2(a, b, c, false);
#else
    return c + (float)a[0] * (float)b[0] + (float)a[1] * (float)b[1];
#endif
}

// ---------------------------------------------------------------------------
// prep_u4: all four U matrices in one launch (grid 2048).
// Uf[g*131072 + k2*1024 + col] = (U_g[2k2][col], U_g[2k2+1][col]) as 2xf16
// ---------------------------------------------------------------------------
__global__ __launch_bounds__(256) void prep_u4(const float* __restrict__ U0,
                                               const float* __restrict__ U1,
                                               const float* __restrict__ U2,
                                               const float* __restrict__ U3,
                                               unsigned int* __restrict__ Uf) {
    int g = blockIdx.x >> 9;  // 0..3
    int idx = (blockIdx.x & 511) * 256 + threadIdx.x;  // < 131072
    const float* U = (g == 0) ? U0 : (g == 1) ? U1 : (g == 2) ? U2 : U3;
    int k2 = idx >> 10, col = idx & 1023;
    union { _Float16 h[2]; unsigned int u; } p;
    p.h[0] = (_Float16)U[(2 * k2) * 1024 + col];
    p.h[1] = (_Float16)U[(2 * k2 + 1) * 1024 + col];
    Uf[g * 131072 + idx] = p.u;
}

// ---------------------------------------------------------------------------
// gemm2: paired f32 GEMM. blockIdx.z selects {B,bias,C,revA}; both halves of
// a layer run concurrently (256 blocks fill the 256-CU chip).
// C[M,N] = opA(A)[M,K] @ B[K,N] + bias[N].
// Inner loop: 2 x ds_read_b128 per kp (acc remap r=4ty+i, c=4tx+j); LDS pad
// 68 floats keeps staging writes 2-way (free) and rows 16B-aligned.
// ---------------------------------------------------------------------------
__global__ __launch_bounds__(256) void gemm2(const float* __restrict__ A,
                                             const float* __restrict__ B0,
                                             const float* __restrict__ B1,
                                             const float* __restrict__ bias0,
                                             const float* __restrict__ bias1,
                                             float* __restrict__ C0,
                                             float* __restrict__ C1,
                                             int M, int N, int K, int rev1) {
    const float* B = blockIdx.z ? B1 : B0;
    const float* bias = blockIdx.z ? bias1 : bias0;
    float* C = blockIdx.z ? C1 : C0;
    int revA = blockIdx.z ? rev1 : 0;

    __shared__ __align__(16) float sA[16][68];
    __shared__ __align__(16) float sB[16][68];
    int tid = threadIdx.x;
    int bm = blockIdx.y * 64, bn = blockIdx.x * 64;
    int tx = tid & 15, ty = tid >> 4;
    float acc[4][4] = {};
    for (int k0 = 0; k0 < K; k0 += 16) {
#pragma unroll
        for (int l = 0; l < 4; l++) {
            int flat = tid + 256 * l;
            int ml = flat >> 4, kk = flat & 15;
            int row = bm + ml;
            if (revA) row = M - 1 - row;
            sA[kk][ml] = A[row * K + k0 + kk];
        }
#pragma unroll
        for (int l = 0; l < 4; l++) {
            int flat = tid + 256 * l;
            int kk = flat >> 6, nl = flat & 63;
            sB[kk][nl] = B[(k0 + kk) * N + bn + nl];
        }
        __syncthreads();
#pragma unroll
        for (int kk = 0; kk < 16; kk++) {
            float4 av = *(const float4*)&sA[kk][4 * ty];
            float4 bv = *(const float4*)&sB[kk][4 * tx];
            float a[4] = {av.x, av.y, av.z, av.w};
            float b[4] = {bv.x, bv.y, bv.z, bv.w};
#pragma unroll
            for (int i = 0; i < 4; i++)
#pragma unroll
                for (int j = 0; j < 4; j++) acc[i][j] += a[i] * b[j];
        }
        __syncthreads();
    }
    float4 bb = make_float4(0.f, 0.f, 0.f, 0.f);
    if (bias) bb = *(const float4*)&bias[bn + 4 * tx];
#pragma unroll
    for (int i = 0; i < 4; i++) {
        int r = bm + 4 * ty + i;
        float4 cv = make_float4(acc[i][0] + bb.x, acc[i][1] + bb.y,
                                acc[i][2] + bb.z, acc[i][3] + bb.w);
        *(float4*)&C[r * N + bn + 4 * tx] = cv;
    }
}

// ---------------------------------------------------------------------------
// lstm_duo: 4 blocks (2 per direction) x 512 threads. Core is BYTE-IDENTICAL
// to the ROUND-7 VERIFIED kernel (961us/dispatch, passed, VGPR=88: the
// 64-reg pin + ~24 working fits the 128 grant @512thr). Single delta (same
// transformation that took r5->r14 for the quad): the h store scatters
// directly into the concat layout, eliminating concat_k.
//
// Design: block b owns units [128b,128b+128) with all 4 gate columns
// (col = 256*gate + 128*b + u; 512 cols, 1 col/thread). kp[0,64) in LDS
// (128KB), kp[64,128) in 8 x u32x8 = 64 VGPRs. Dots split by h-ownership so
// the LLC round trip overlaps compute: probe remote slot -> Phase A
// (own-half kp; own h already local) -> finish poll (peer published a full
// phase earlier; s_sleep backoff) -> Phase B (remote-half kp) -> gates ->
// publish-FIRST (tagged store before O/sH writes). Tagged-entry protocol:
// 8B relaxed agent-scope atomics {tag=step+1 | packed f16 pair}, parity
// double-buffered; writer reuses a slot 2 steps later and its own poll of
// the peer's s+2 tag proves s+1 was consumed; memset zeros = step-0 tags.
// ---------------------------------------------------------------------------
#define UAq(r) ((r) < 8 ? q0[(r) & 7] : (r) < 16 ? q1[(r) & 7] : \
                (r) < 24 ? q2[(r) & 7] : (r) < 32 ? q3[(r) & 7] : \
                (r) < 40 ? q4[(r) & 7] : (r) < 48 ? q5[(r) & 7] : \
                (r) < 56 ? q6[(r) & 7] : q7[(r) & 7])

// dots over LDS-resident kp [0,64)  <-> h chunks hp4[0..16)  (k in [0,128))
#define DOTS_LDS(accA, accB)                                   \
    _Pragma("unroll") for (int cch = 0; cch < 16; cch++) {     \
        uint4 hc = hp4[cch];                                   \
        const unsigned int* su = &sU[(4 * cch) * 512 + t];     \
        accA = fdot2f(BC(hc.x), BC(su[0]), accA);              \
        accB = fdot2f(BC(hc.y), BC(su[512]), accB);            \
        accA = fdot2f(BC(hc.z), BC(su[1024]), accA);           \
        accB = fdot2f(BC(hc.w), BC(su[1536]), accB);           \
    }

// dots over reg-resident kp [64,128) <-> h chunks hp4[16..32) (k in [128,256))
#define DOTS_REG(accA, accB)                                   \
    _Pragma("unroll") for (int cch = 16; cch < 32; cch++) {    \
        uint4 hc = hp4[cch];                                   \
        const int r0 = 4 * (cch - 16);                         \
        accA = fdot2f(BC(hc.x), BC(UAq(r0 + 0)), accA);        \
        accB = fdot2f(BC(hc.y), BC(UAq(r0 + 1)), accB);        \
        accA = fdot2f(BC(hc.z), BC(UAq(r0 + 2)), accA);        \
        accB = fdot2f(BC(hc.w), BC(UAq(r0 + 3)), accB);        \
    }

__global__ __launch_bounds__(512) void lstm_duo(
        const unsigned int* __restrict__ Ua, const unsigned int* __restrict__ Ub,
        const float* __restrict__ Pa, const float* __restrict__ Pb,
        float* __restrict__ Ov, unsigned long long* Hg) {
    int dir = blockIdx.x >> 1;  // 0 = fwd, 1 = bwd
    int b = blockIdx.x & 1;     // owns hidden units [128b, 128b+128)
    const unsigned int* U = dir ? Ub : Ua;
    const float* P = dir ? Pb : Pa;
    // per dir: 2 parity x 2 halves x 64 tagged entries
    unsigned long long* Hgd = Hg + dir * 256;

    __shared__ unsigned int sU[64 * 512];            // 131072 B, kp-major
    __shared__ __align__(16) unsigned int sH[128];   // h as packed f16 pairs
    __shared__ float sZ[512];

    int t = threadIdx.x;  // 0..511
    // gate g = t>>7, unit u = t&127; column in the 4L z-vector:
    int col = ((t >> 7) << 8) + (b << 7) + (t & 127);

    // stage kp [0,64) of this block's 512 columns into LDS
    for (int kp = 0; kp < 64; kp++) sU[kp * 512 + t] = U[kp * 1024 + col];

    // kp [64,128) register-resident: 8 x 8-wide SSA vectors = 64 VGPRs
    u32x8 q0, q1, q2, q3, q4, q5, q6, q7;
#pragma unroll
    for (int j = 0; j < 8; j++) {
        q0[j] = U[(64 + j) * 1024 + col];
        q1[j] = U[(72 + j) * 1024 + col];
        q2[j] = U[(80 + j) * 1024 + col];
        q3[j] = U[(88 + j) * 1024 + col];
        q4[j] = U[(96 + j) * 1024 + col];
        q5[j] = U[(104 + j) * 1024 + col];
        q6[j] = U[(112 + j) * 1024 + col];
        q7[j] = U[(120 + j) * 1024 + col];
    }
    asm volatile(""
                 : "+v"(q0), "+v"(q1), "+v"(q2), "+v"(q3),
                   "+v"(q4), "+v"(q5), "+v"(q6), "+v"(q7));

    if (t < 128) sH[t] = 0u;
    float c0 = 0.f, c1 = 0.f;  // gate threads: cell state for units 2t, 2t+1
    __syncthreads();

    const uint4* hp4 = (const uint4*)sH;  // 32 chunks x (4 h2v) = 256 h
    float pc = P[col];
    for (int step = 0; step < 512; step++) {
        float pn = pc;
        if (step < 511) pn = P[(step + 1) * 1024 + col];

        // early probe of the remote tagged slot (expects tag == step)
        unsigned long long* rslot = nullptr;
        unsigned long long rv = 0;
        if (t >= 64 && t < 128) {
            rslot = &Hgd[(step & 1) * 128 + (1 - b) * 64 + (t - 64)];
            rv = __hip_atomic_load(rslot, __ATOMIC_RELAXED,
                                   __HIP_MEMORY_SCOPE_AGENT);
        }

        // Phase A: own-half dots (own h written locally at end of prev step)
        float a0 = pc, a1 = 0.f;
        if (b == 0) { DOTS_LDS(a0, a1) } else { DOTS_REG(a0, a1) }

        // finish poll (s_sleep backoff on miss), land remote h(step-1)
        if (t >= 64 && t < 128) {
            unsigned long long v = rv;
            unsigned long long want = (unsigned long long)step;
            while ((v >> 32) != want) {
                __builtin_amdgcn_s_sleep(1);
                v = __hip_atomic_load(rslot, __ATOMIC_RELAXED,
                                      __HIP_MEMORY_SCOPE_AGENT);
            }
            sH[(1 - b) * 64 + (t - 64)] = (unsigned int)v;
        }
        __syncthreads();

        // Phase B: remote-half dots
        float a2 = 0.f, a3 = 0.f;
        if (b == 0) { DOTS_REG(a2, a3) } else { DOTS_LDS(a2, a3) }

        sZ[t] = (a0 + a1) + (a2 + a3);
        __syncthreads();

        if (t < 64) {  // gates for local units 2t, 2t+1 (single wave)
            float2 z0 = ((const float2*)sZ)[t];          // i
            float2 z1 = ((const float2*)(sZ + 128))[t];  // f
            float2 z2 = ((const float2*)(sZ + 256))[t];  // g
            float2 z3 = ((const float2*)(sZ + 384))[t];  // o
            float ig0 = 1.f / (1.f + __expf(-z0.x));
            float fg0 = 1.f / (1.f + __expf(-z1.x));
            float gg0 = 1.f - 2.f / (1.f + __expf(2.f * z2.x));
            float og0 = 1.f / (1.f + __expf(-z3.x));
            c0 = fg0 * c0 + ig0 * gg0;
            float h0 = og0 * (1.f - 2.f / (1.f + __expf(2.f * c0)));
            float ig1 = 1.f / (1.f + __expf(-z0.y));
            float fg1 = 1.f / (1.f + __expf(-z1.y));
            float gg1 = 1.f - 2.f / (1.f + __expf(2.f * z2.y));
            float og1 = 1.f / (1.f + __expf(-z3.y));
            c1 = fg1 * c1 + ig1 * gg1;
            float h1 = og1 * (1.f - 2.f / (1.f + __expf(2.f * c1)));
            // publish FIRST: LLC propagation overlaps the epilogue + barrier
            union { _Float16 hh[2]; unsigned int u; } pk;
            pk.hh[0] = (_Float16)h0;
            pk.hh[1] = (_Float16)h1;
            unsigned long long v =
                ((unsigned long long)(step + 1) << 32) | (unsigned long long)pk.u;
            __hip_atomic_store(&Hgd[((step + 1) & 1) * 128 + (b << 6) + t], v,
                               __ATOMIC_RELAXED, __HIP_MEMORY_SCOPE_AGENT);
            // direct concat-layout store (replaces concat_k):
            // fwd: v[step][128b+2t..+1]; bwd: v[511-step][256+128b+2t..+1]
            int orow = dir ? (511 - step) : step;
            ((float2*)(Ov + orow * 512 + (dir << 8) + (b << 7)))[t] =
                make_float2(h0, h1);
            sH[(b << 6) + t] = pk.u;  // own half locally
        }
        __syncthreads();
        pc = pn;
    }
}

// ---------------------------------------------------------------------------
// head: S[i][j] = sum_h tanh(HF[i][h] + MF[j][h]) * w[h] + outBias
// ---------------------------------------------------------------------------
__global__ __launch_bounds__(256) void head_kernel(const float* __restrict__ HF,
                                                   const float* __restrict__ MF,
                                                   const float* __restrict__ w,
                                                   const float* __restrict__ outb,
                                                   float* __restrict__ S) {
    int i = blockIdx.x;
    __shared__ float sHF[512], sW[512];
    int tid = threadIdx.x;
    sHF[tid] = HF[i * 512 + tid];
    sHF[tid + 256] = HF[i * 512 + 256 + tid];
    sW[tid] = w[tid];
    sW[tid + 256] = w[tid + 256];
    __syncthreads();
    int lane = tid & 63, wv = tid >> 6;
    float ob = outb[0];
    for (int j = wv; j < 512; j += 4) {
        const float* mf = MF + j * 512;
        float acc = 0.f;
#pragma unroll
        for (int r = 0; r < 8; r++) {
            int h = lane + 64 * r;
            float x = sHF[h] + mf[h];
            acc += sW[h] * (1.f - 2.f / (1.f + __expf(2.f * x)));
        }
#pragma unroll
        for (int off = 32; off; off >>= 1) acc += __shfl_down(acc, off);
        if (lane == 0) S[i * 512 + j] = acc + ob;
    }
}

// ---------------------------------------------------------------------------
extern "C" void kernel_launch(void* const* d_in, const int* in_sizes, int n_in,
                              void* d_out, int out_size, void* d_ws, size_t ws_size,
                              hipStream_t stream) {
    const float* emb      = (const float*)d_in[0];
    const float* W_f1     = (const float*)d_in[1];
    const float* U_f1     = (const float*)d_in[2];
    const float* b_f1     = (const float*)d_in[3];
    const float* W_b1     = (const float*)d_in[4];
    const float* U_b1     = (const float*)d_in[5];
    const float* b_b1     = (const float*)d_in[6];
    const float* W_f2     = (const float*)d_in[7];
    const float* U_f2     = (const float*)d_in[8];
    const float* b_f2     = (const float*)d_in[9];
    const float* W_b2     = (const float*)d_in[10];
    const float* U_b2     = (const float*)d_in[11];
    const float* b_b2     = (const float*)d_in[12];
    const float* FOH      = (const float*)d_in[13];
    const float* FOM      = (const float*)d_in[14];
    const float* hidBias  = (const float*)d_in[15];
    const float* outLayer = (const float*)d_in[16];
    const float* outBias  = (const float*)d_in[17];
    float* out = (float*)d_out;

    // workspace carve (16 MB total)
    unsigned int* uf = (unsigned int*)d_ws;          // 4 x 131072 uints = 2MB
    unsigned int* uf_f1 = uf;
    unsigned int* uf_b1 = uf + 131072;
    unsigned int* uf_f2 = uf + 262144;
    unsigned int* uf_b2 = uf + 393216;
    float* f = (float*)d_ws + 524288;
    float* P1f = f;                 // 512x1024
    float* P1b = f + 524288;
    float* P2f = f + 1048576;
    float* P2b = f + 1572864;
    float* v    = f + 2621440;      // 512x512 (lstm1 writes concat directly)
    float* hcat = f + 2883584;      // 512x512 (lstm2 writes concat directly)
    float* HFb  = f + 3145728;      // 512x512 (includes hidBias)
    float* MFb  = f + 3407872;
    // sync region aliases MFb (dead during both lstm dispatches: MFb is only
    // written by the last gemm2 and read by head, both after lstm-2).
    // 2 dirs x 2 parity x 2 halves x 64 tagged 8B entries = 4KB.
    unsigned long long* sync = (unsigned long long*)(f + 3407872);

    prep_u4<<<2048, 256, 0, stream>>>(U_f1, U_b1, U_f2, U_b2, uf);

    dim3 g1(1024 / 64, 512 / 64, 2);
    gemm2<<<g1, 256, 0, stream>>>(emb, W_f1, W_b1, b_f1, b_b1, P1f, P1b,
                                  512, 1024, 256, 1);

    hipMemsetAsync(sync, 0, 4096, stream);
    lstm_duo<<<4, 512, 0, stream>>>(uf_f1, uf_b1, P1f, P1b, v, sync);

    gemm2<<<g1, 256, 0, stream>>>(v, W_f2, W_b2, b_f2, b_b2, P2f, P2b,
                                  512, 1024, 512, 1);

    hipMemsetAsync(sync, 0, 4096, stream);
    lstm_duo<<<4, 512, 0, stream>>>(uf_f2, uf_b2, P2f, P2b, hcat, sync);

    dim3 g2(512 / 64, 512 / 64, 2);
    gemm2<<<g2, 256, 0, stream>>>(hcat, FOH, FOM, hidBias, nullptr, HFb, MFb,
                                  512, 512, 512, 0);

    head_kernel<<<512, 256, 0, stream>>>(HFb, MFb, outLayer, outBias, out);
}

// Round 16
// 2250.592 us; speedup vs baseline: 1.0566x; 1.0566x over previous
//
#include <hip/hip_runtime.h>
#include <hip/hip_bf16.h>

// Sizes (fixed): T=512 tokens, D=256 embed, L=256 lstm, H=512 hidden. 4L=1024.

typedef _Float16 h2v __attribute__((ext_vector_type(2)));
typedef unsigned int u32x8 __attribute__((ext_vector_type(8)));

#define BC(x) __builtin_bit_cast(h2v, (x))

__device__ __forceinline__ float fdot2f(h2v a, h2v b, float c) {
#if __has_builtin(__builtin_amdgcn_fdot2)
    return __builtin_amdgcn_fdot2(a, b, c, false);
#else
    return c + (float)a[0] * (float)b[0] + (float)a[1] * (float)b[1];
#endif
}

// ---------------------------------------------------------------------------
// prep_u4: all four U matrices in one launch (grid 2048).
// Uf[g*131072 + k2*1024 + col] = (U_g[2k2][col], U_g[2k2+1][col]) as 2xf16
// ---------------------------------------------------------------------------
__global__ __launch_bounds__(256) void prep_u4(const float* __restrict__ U0,
                                               const float* __restrict__ U1,
                                               const float* __restrict__ U2,
                                               const float* __restrict__ U3,
                                               unsigned int* __restrict__ Uf) {
    int g = blockIdx.x >> 9;  // 0..3
    int idx = (blockIdx.x & 511) * 256 + threadIdx.x;  // < 131072
    const float* U = (g == 0) ? U0 : (g == 1) ? U1 : (g == 2) ? U2 : U3;
    int k2 = idx >> 10, col = idx & 1023;
    union { _Float16 h[2]; unsigned int u; } p;
    p.h[0] = (_Float16)U[(2 * k2) * 1024 + col];
    p.h[1] = (_Float16)U[(2 * k2 + 1) * 1024 + col];
    Uf[g * 131072 + idx] = p.u;
}

// ---------------------------------------------------------------------------
// gemm2: paired f32 GEMM. blockIdx.z selects {B,bias,C,revA}; both halves of
// a layer run concurrently (256 blocks fill the 256-CU chip).
// C[M,N] = opA(A)[M,K] @ B[K,N] + bias[N].
// Inner loop: 2 x ds_read_b128 per kp (acc remap r=4ty+i, c=4tx+j); LDS pad
// 68 floats keeps staging writes 2-way (free) and rows 16B-aligned.
// ---------------------------------------------------------------------------
__global__ __launch_bounds__(256) void gemm2(const float* __restrict__ A,
                                             const float* __restrict__ B0,
                                             const float* __restrict__ B1,
                                             const float* __restrict__ bias0,
                                             const float* __restrict__ bias1,
                                             float* __restrict__ C0,
                                             float* __restrict__ C1,
                                             int M, int N, int K, int rev1) {
    const float* B = blockIdx.z ? B1 : B0;
    const float* bias = blockIdx.z ? bias1 : bias0;
    float* C = blockIdx.z ? C1 : C0;
    int revA = blockIdx.z ? rev1 : 0;

    __shared__ __align__(16) float sA[16][68];
    __shared__ __align__(16) float sB[16][68];
    int tid = threadIdx.x;
    int bm = blockIdx.y * 64, bn = blockIdx.x * 64;
    int tx = tid & 15, ty = tid >> 4;
    float acc[4][4] = {};
    for (int k0 = 0; k0 < K; k0 += 16) {
#pragma unroll
        for (int l = 0; l < 4; l++) {
            int flat = tid + 256 * l;
            int ml = flat >> 4, kk = flat & 15;
            int row = bm + ml;
            if (revA) row = M - 1 - row;
            sA[kk][ml] = A[row * K + k0 + kk];
        }
#pragma unroll
        for (int l = 0; l < 4; l++) {
            int flat = tid + 256 * l;
            int kk = flat >> 6, nl = flat & 63;
            sB[kk][nl] = B[(k0 + kk) * N + bn + nl];
        }
        __syncthreads();
#pragma unroll
        for (int kk = 0; kk < 16; kk++) {
            float4 av = *(const float4*)&sA[kk][4 * ty];
            float4 bv = *(const float4*)&sB[kk][4 * tx];
            float a[4] = {av.x, av.y, av.z, av.w};
            float b[4] = {bv.x, bv.y, bv.z, bv.w};
#pragma unroll
            for (int i = 0; i < 4; i++)
#pragma unroll
                for (int j = 0; j < 4; j++) acc[i][j] += a[i] * b[j];
        }
        __syncthreads();
    }
    float4 bb = make_float4(0.f, 0.f, 0.f, 0.f);
    if (bias) bb = *(const float4*)&bias[bn + 4 * tx];
#pragma unroll
    for (int i = 0; i < 4; i++) {
        int r = bm + 4 * ty + i;
        float4 cv = make_float4(acc[i][0] + bb.x, acc[i][1] + bb.y,
                                acc[i][2] + bb.z, acc[i][3] + bb.w);
        *(float4*)&C[r * N + bn + 4 * tx] = cv;
    }
}

// ---------------------------------------------------------------------------
// lstm_quad: 8 blocks (4 per direction) x 256 threads. Compute/sync core is
// BYTE-IDENTICAL to the round-5/round-13 verified kernel; this whole file is
// the ROUND-14 VERIFIED ARTIFACT (total 2269us, passed; lstm 1036us each).
//
// Round-15 verdict behind this revert: the overlapped duo (2 blocks/dir,
// phase-split dots) measured 1062us here vs quad's stable 1029-1036 across
// three runs -- its mid-step poll sits on the critical path and is
// placement/skew-sensitive (961 once in r7, 1062 in r15, +42ms replay
// outlier). The quad's end-of-step symmetric exchange is robust. All
// architectures converge at the ~2.0us/step LLC round-trip floor; the
// single-CU register-residency route was falsified by the allocator grant
// law (128 VGPR @512thr, pins spill; 192-reg pin @256thr miscompiled).
//
// Design: block b owns hidden units [64b,64b+64) and all four gate columns
// (col = 256*gate + 64*b + u). U-slice = 128kp x 256 cols: kp[0,64) in LDS
// (64KB), kp[64,128) in 8 x u32x8 = 64 VGPRs (VGPR_Count=88, holds).
// Exchange: each h-pair publishes as ONE 8B relaxed agent-scope atomic
// {tag=step+1 | packed f16 pair} in a parity-double-buffered slot; readers
// poll their own entry until the tag matches (tag+data in the same load).
// Parity safety: writer reuses a slot 2 steps later and its own poll of
// peers' s+2 tags proves s+1 was consumed. Stale tags zeroed per dispatch.
// h store scatters directly into the concat layout (fwd: row=step cols
// [64b,64b+64); bwd: row=511-step cols [256+64b,...)) -- no concat kernel.
// ---------------------------------------------------------------------------
#define UAq(r) ((r) < 8 ? q0[(r) & 7] : (r) < 16 ? q1[(r) & 7] : \
                (r) < 24 ? q2[(r) & 7] : (r) < 32 ? q3[(r) & 7] : \
                (r) < 40 ? q4[(r) & 7] : (r) < 48 ? q5[(r) & 7] : \
                (r) < 56 ? q6[(r) & 7] : q7[(r) & 7])

__global__ __launch_bounds__(256) void lstm_quad(
        const unsigned int* __restrict__ Ua, const unsigned int* __restrict__ Ub,
        const float* __restrict__ Pa, const float* __restrict__ Pb,
        float* __restrict__ Ov, unsigned long long* Hg) {
    int dir = blockIdx.x >> 2;  // 0 = fwd, 1 = bwd
    int b = blockIdx.x & 3;     // owns hidden units [64b, 64b+64)
    const unsigned int* U = dir ? Ub : Ua;
    const float* P = dir ? Pb : Pa;
    // per dir: 2 parity buffers x 128 entries (4 blocks x 32 h-pairs)
    unsigned long long* Hgd = Hg + dir * 256;

    __shared__ unsigned int sU[64 * 256];            // 65536 B, kp-major slice
    __shared__ __align__(16) unsigned int sH[128];   // h as packed f16 pairs
    __shared__ float sZ[256];
    __shared__ float sG[64];

    int t = threadIdx.x;  // 0..255
    // gate g = t>>6, unit u = t&63; global column in the 4L z-vector:
    int col = ((t >> 6) << 8) + (b << 6) + (t & 63);

    // stage kp [0,64) of this block's 256 columns into LDS
    for (int kp = 0; kp < 64; kp++) sU[kp * 256 + t] = U[kp * 1024 + col];

    // kp [64,128) register-resident: 8 x 8-wide SSA vectors = 64 VGPRs
    u32x8 q0, q1, q2, q3, q4, q5, q6, q7;
#pragma unroll
    for (int j = 0; j < 8; j++) {
        q0[j] = U[(64 + j) * 1024 + col];
        q1[j] = U[(72 + j) * 1024 + col];
        q2[j] = U[(80 + j) * 1024 + col];
        q3[j] = U[(88 + j) * 1024 + col];
        q4[j] = U[(96 + j) * 1024 + col];
        q5[j] = U[(104 + j) * 1024 + col];
        q6[j] = U[(112 + j) * 1024 + col];
        q7[j] = U[(120 + j) * 1024 + col];
    }
    asm volatile(""
                 : "+v"(q0), "+v"(q1), "+v"(q2), "+v"(q3),
                   "+v"(q4), "+v"(q5), "+v"(q6), "+v"(q7));

    if (t < 128) sH[t] = 0u;
    float c = 0.f;
    __syncthreads();

    const uint4* hp4 = (const uint4*)sH;  // 32 chunks x (4 h2v) = 256 h
    float pc = P[col];
    for (int step = 0; step < 512; step++) {
        float pn = pc;
        if (step < 511) pn = P[(step + 1) * 1024 + col];
        float a0 = pc, a1 = 0.f, a2 = 0.f, a3 = 0.f;  // 4 indep dep-chains

        // kp [0,64) from LDS (lane-consecutive b32, conflict-free)
#pragma unroll
        for (int cch = 0; cch < 16; cch++) {
            uint4 hc = hp4[cch];
            const unsigned int* su = &sU[(4 * cch) * 256 + t];
            a0 = fdot2f(BC(hc.x), BC(su[0]), a0);
            a1 = fdot2f(BC(hc.y), BC(su[256]), a1);
            a2 = fdot2f(BC(hc.z), BC(su[512]), a2);
            a3 = fdot2f(BC(hc.w), BC(su[768]), a3);
        }
        // kp [64,128) from registers
#pragma unroll
        for (int cch = 16; cch < 32; cch++) {
            uint4 hc = hp4[cch];
            const int r0 = 4 * (cch - 16);
            a0 = fdot2f(BC(hc.x), BC(UAq(r0 + 0)), a0);
            a1 = fdot2f(BC(hc.y), BC(UAq(r0 + 1)), a1);
            a2 = fdot2f(BC(hc.z), BC(UAq(r0 + 2)), a2);
            a3 = fdot2f(BC(hc.w), BC(UAq(r0 + 3)), a3);
        }
        sZ[t] = (a0 + a1) + (a2 + a3);
        __syncthreads();

        unsigned long long* Hbuf = Hgd + ((step + 1) & 1) * 128;  // parity
        unsigned long long tag = (unsigned long long)(step + 1);
        if (t < 64) {
            float zi = sZ[t], zf = sZ[64 + t], zg = sZ[128 + t], zo = sZ[192 + t];
            float ig = 1.f / (1.f + __expf(-zi));
            float fg = 1.f / (1.f + __expf(-zf));
            float gg = 1.f - 2.f / (1.f + __expf(2.f * zg));   // tanh
            float og = 1.f / (1.f + __expf(-zo));
            c = fg * c + ig * gg;
            float h = og * (1.f - 2.f / (1.f + __expf(2.f * c)));
            // direct concat-layout store (replaces concat_k):
            // fwd: v[step][64b+t]; bwd: v[511-step][256+64b+t]
            int orow = dir ? (511 - step) : step;
            Ov[orow * 512 + (dir << 8) + (b << 6) + t] = h;
            sG[t] = h;  // wave 0 only: LDS ops below are same-wave ordered
            if (t < 32) {
                union { _Float16 hh[2]; unsigned int u; } pk;
                pk.hh[0] = (_Float16)sG[2 * t];
                pk.hh[1] = (_Float16)sG[2 * t + 1];
                unsigned long long v = (tag << 32) | (unsigned long long)pk.u;
                __hip_atomic_store(&Hbuf[(b << 5) + t], v, __ATOMIC_RELAXED,
                                   __HIP_MEMORY_SCOPE_AGENT);
            }
        }
        // single-round-trip poll: tag+data arrive in the same 8B load
        if (t < 128) {
            unsigned long long v;
            do {
                v = __hip_atomic_load(&Hbuf[t], __ATOMIC_RELAXED,
                                      __HIP_MEMORY_SCOPE_AGENT);
            } while ((v >> 32) != tag);
            sH[t] = (unsigned int)v;
        }
        __syncthreads();
        pc = pn;
    }
}

// ---------------------------------------------------------------------------
// head: S[i][j] = sum_h tanh(HF[i][h] + MF[j][h]) * w[h] + outBias
// ---------------------------------------------------------------------------
__global__ __launch_bounds__(256) void head_kernel(const float* __restrict__ HF,
                                                   const float* __restrict__ MF,
                                                   const float* __restrict__ w,
                                                   const float* __restrict__ outb,
                                                   float* __restrict__ S) {
    int i = blockIdx.x;
    __shared__ float sHF[512], sW[512];
    int tid = threadIdx.x;
    sHF[tid] = HF[i * 512 + tid];
    sHF[tid + 256] = HF[i * 512 + 256 + tid];
    sW[tid] = w[tid];
    sW[tid + 256] = w[tid + 256];
    __syncthreads();
    int lane = tid & 63, wv = tid >> 6;
    float ob = outb[0];
    for (int j = wv; j < 512; j += 4) {
        const float* mf = MF + j * 512;
        float acc = 0.f;
#pragma unroll
        for (int r = 0; r < 8; r++) {
            int h = lane + 64 * r;
            float x = sHF[h] + mf[h];
            acc += sW[h] * (1.f - 2.f / (1.f + __expf(2.f * x)));
        }
#pragma unroll
        for (int off = 32; off; off >>= 1) acc += __shfl_down(acc, off);
        if (lane == 0) S[i * 512 + j] = acc + ob;
    }
}

// ---------------------------------------------------------------------------
extern "C" void kernel_launch(void* const* d_in, const int* in_sizes, int n_in,
                              void* d_out, int out_size, void* d_ws, size_t ws_size,
                              hipStream_t stream) {
    const float* emb      = (const float*)d_in[0];
    const float* W_f1     = (const float*)d_in[1];
    const float* U_f1     = (const float*)d_in[2];
    const float* b_f1     = (const float*)d_in[3];
    const float* W_b1     = (const float*)d_in[4];
    const float* U_b1     = (const float*)d_in[5];
    const float* b_b1     = (const float*)d_in[6];
    const float* W_f2     = (const float*)d_in[7];
    const float* U_f2     = (const float*)d_in[8];
    const float* b_f2     = (const float*)d_in[9];
    const float* W_b2     = (const float*)d_in[10];
    const float* U_b2     = (const float*)d_in[11];
    const float* b_b2     = (const float*)d_in[12];
    const float* FOH      = (const float*)d_in[13];
    const float* FOM      = (const float*)d_in[14];
    const float* hidBias  = (const float*)d_in[15];
    const float* outLayer = (const float*)d_in[16];
    const float* outBias  = (const float*)d_in[17];
    float* out = (float*)d_out;

    // workspace carve (16 MB total)
    unsigned int* uf = (unsigned int*)d_ws;          // 4 x 131072 uints = 2MB
    unsigned int* uf_f1 = uf;
    unsigned int* uf_b1 = uf + 131072;
    unsigned int* uf_f2 = uf + 262144;
    unsigned int* uf_b2 = uf + 393216;
    float* f = (float*)d_ws + 524288;
    float* P1f = f;                 // 512x1024
    float* P1b = f + 524288;
    float* P2f = f + 1048576;
    float* P2b = f + 1572864;
    float* v    = f + 2621440;      // 512x512 (lstm1 writes concat directly)
    float* hcat = f + 2883584;      // 512x512 (lstm2 writes concat directly)
    float* HFb  = f + 3145728;      // 512x512 (includes hidBias)
    float* MFb  = f + 3407872;
    // sync region aliases MFb (dead during both lstm dispatches: MFb is only
    // written by the last gemm2 and read by head, both after lstm-2).
    // 2 dirs x 2 parity x 128 tagged 8B entries = 4KB.
    unsigned long long* sync = (unsigned long long*)(f + 3407872);

    prep_u4<<<2048, 256, 0, stream>>>(U_f1, U_b1, U_f2, U_b2, uf);

    dim3 g1(1024 / 64, 512 / 64, 2);
    gemm2<<<g1, 256, 0, stream>>>(emb, W_f1, W_b1, b_f1, b_b1, P1f, P1b,
                                  512, 1024, 256, 1);

    hipMemsetAsync(sync, 0, 4096, stream);
    lstm_quad<<<8, 256, 0, stream>>>(uf_f1, uf_b1, P1f, P1b, v, sync);

    gemm2<<<g1, 256, 0, stream>>>(v, W_f2, W_b2, b_f2, b_b2, P2f, P2b,
                                  512, 1024, 512, 1);

    hipMemsetAsync(sync, 0, 4096, stream);
    lstm_quad<<<8, 256, 0, stream>>>(uf_f2, uf_b2, P2f, P2b, hcat, sync);

    dim3 g2(512 / 64, 512 / 64, 2);
    gemm2<<<g2, 256, 0, stream>>>(hcat, FOH, FOM, hidBias, nullptr, HFb, MFb,
                                  512, 512, 512, 0);

    head_kernel<<<512, 256, 0, stream>>>(HFb, MFb, outLayer, outBias, out);
}